// Round 1
// 712.799 us; speedup vs baseline: 1.1025x; 1.1025x over previous
//
#include <hip/hip_runtime.h>

#define Bn 4
#define Cn 256
#define Hn 256
#define Wn 256
#define Rn 64
#define HL 64
#define WL 64
#define PIX (HL*WL)   // 4096 low-res pixels per (b, channel)

// ---------------------------------------------------------------------------
// K1: bilinear 1/4 downsample of F_enc and F_dec (NCHW).
// scale=4 => src = 4*i + 1.5 => avg of elements 4i+1, 4i+2 per axis.
// One thread per FOUR low-res outputs (one float4 along x): 8 float4 loads,
// 1 float4 store, 1/4 the index math of the scalar version.
__global__ __launch_bounds__(256) void k_downsample(
    const float* __restrict__ src0, const float* __restrict__ src1,
    float* __restrict__ dst0, float* __restrict__ dst1) {
  const float* __restrict__ src = blockIdx.y ? src1 : src0;
  float* __restrict__ dst       = blockIdx.y ? dst1 : dst0;
  int idx = blockIdx.x * 256 + threadIdx.x;     // B*C*HL*WL/4 = 1,048,576
  int xq = idx & 15;            // which float4 within the 64-wide low-res row
  int y  = (idx >> 4) & 63;
  int bc = idx >> 10;
  const float* p = src + ((size_t)bc * Hn + (4 * y + 1)) * Wn + 16 * xq;
  float4 a0 = *(const float4*)(p);
  float4 a1 = *(const float4*)(p + 4);
  float4 a2 = *(const float4*)(p + 8);
  float4 a3 = *(const float4*)(p + 12);
  float4 c0 = *(const float4*)(p + Wn);
  float4 c1 = *(const float4*)(p + Wn + 4);
  float4 c2 = *(const float4*)(p + Wn + 8);
  float4 c3 = *(const float4*)(p + Wn + 12);
  float4 o;
  o.x = 0.25f * (a0.y + a0.z + c0.y + c0.z);
  o.y = 0.25f * (a1.y + a1.z + c1.y + c1.z);
  o.z = 0.25f * (a2.y + a2.z + c2.y + c2.z);
  o.w = 0.25f * (a3.y + a3.z + c3.y + c3.z);
  ((float4*)dst)[idx] = o;
}

// ---------------------------------------------------------------------------
// K2: low-res 1x1 conv C->R:  fg[b,r,p] = sum_c E_ds[b,c,p] * w[r,c]
// Block: 256 threads = 256 pixels; handles 16 r values (acc in regs).
__global__ __launch_bounds__(256) void k_reduce_c(
    const float* __restrict__ E, const float* __restrict__ D,
    const float* __restrict__ w_rg, const float* __restrict__ w_rt,
    float* __restrict__ fg, float* __restrict__ ft) {
  int chunk = blockIdx.x;           // 16 chunks of 256 pixels
  int rg    = blockIdx.y;           // 4 groups of 16 r
  int tb    = blockIdx.z;           // t*4 + b
  int t = tb >> 2, b = tb & 3;
  const float* __restrict__ src = (t ? D : E) + (size_t)b * Cn * PIX + chunk * 256 + threadIdx.x;
  const float* __restrict__ wm  = (t ? w_rt : w_rg) + (size_t)(rg * 16) * Cn;
  float acc[16];
#pragma unroll
  for (int j = 0; j < 16; ++j) acc[j] = 0.f;
  for (int c = 0; c < Cn; c += 4) {
    float e0 = src[(size_t)(c + 0) * PIX];
    float e1 = src[(size_t)(c + 1) * PIX];
    float e2 = src[(size_t)(c + 2) * PIX];
    float e3 = src[(size_t)(c + 3) * PIX];
#pragma unroll
    for (int j = 0; j < 16; ++j) {
      float4 wv = *(const float4*)(wm + j * Cn + c);
      acc[j] = fmaf(e0, wv.x, acc[j]);
      acc[j] = fmaf(e1, wv.y, acc[j]);
      acc[j] = fmaf(e2, wv.z, acc[j]);
      acc[j] = fmaf(e3, wv.w, acc[j]);
    }
  }
  float* __restrict__ dst = (t ? ft : fg) + (size_t)b * Rn * PIX + (size_t)(rg * 16) * PIX
                            + chunk * 256 + threadIdx.x;
#pragma unroll
  for (int j = 0; j < 16; ++j) dst[(size_t)j * PIX] = acc[j];
}

// ---------------------------------------------------------------------------
// K3: 3x3 box stats (zero-pad, /9 everywhere) + guided-filter solve.
__global__ __launch_bounds__(256) void k_box_ab(
    const float* __restrict__ fg, const float* __restrict__ ft,
    const float* __restrict__ d_eps,
    float* __restrict__ a_o, float* __restrict__ b_o) {
  int idx = blockIdx.x * 256 + threadIdx.x;   // B*R*PIX = 1,048,576
  int x  = idx & 63;
  int y  = (idx >> 6) & 63;
  int br = idx >> 12;
  const float* __restrict__ g = fg + (size_t)br * PIX;
  const float* __restrict__ t = ft + (size_t)br * PIX;
  float sg = 0.f, st = 0.f, sgg = 0.f, sgt = 0.f;
#pragma unroll
  for (int dy = -1; dy <= 1; ++dy) {
    int yy = y + dy;
    if (yy < 0 || yy > 63) continue;
#pragma unroll
    for (int dx = -1; dx <= 1; ++dx) {
      int xx = x + dx;
      if (xx < 0 || xx > 63) continue;
      float gv = g[yy * 64 + xx];
      float tv = t[yy * 64 + xx];
      sg += gv; st += tv; sgg += gv * gv; sgt += gv * tv;
    }
  }
  const float inv9 = 1.0f / 9.0f;
  float mg  = sg * inv9, mt = st * inv9;
  float var = sgg * inv9 - mg * mg;
  float cov = sgt * inv9 - mg * mt;
  float av  = cov / (var + d_eps[0]);
  a_o[idx] = av;
  b_o[idx] = mt - av * mg;
}

// ---------------------------------------------------------------------------
// K4: low-res 1x1 conv R->C:  A[b,o,p] = sum_r a[b,r,p] * w_ua[o,r]
__global__ __launch_bounds__(256) void k_expand_r(
    const float* __restrict__ a_i, const float* __restrict__ b_i,
    const float* __restrict__ w_ua, const float* __restrict__ w_ub,
    float* __restrict__ A, float* __restrict__ Bb) {
  int chunk = blockIdx.x;           // 16
  int og    = blockIdx.y;           // 16 groups of 16 out-channels
  int tb    = blockIdx.z;           // t*4 + b
  int t = tb >> 2, b = tb & 3;
  const float* __restrict__ src = (t ? b_i : a_i) + (size_t)b * Rn * PIX + chunk * 256 + threadIdx.x;
  const float* __restrict__ wm  = (t ? w_ub : w_ua) + (size_t)(og * 16) * Rn;
  float acc[16];
#pragma unroll
  for (int j = 0; j < 16; ++j) acc[j] = 0.f;
  for (int r = 0; r < Rn; r += 4) {
    float e0 = src[(size_t)(r + 0) * PIX];
    float e1 = src[(size_t)(r + 1) * PIX];
    float e2 = src[(size_t)(r + 2) * PIX];
    float e3 = src[(size_t)(r + 3) * PIX];
#pragma unroll
    for (int j = 0; j < 16; ++j) {
      float4 wv = *(const float4*)(wm + j * Rn + r);
      acc[j] = fmaf(e0, wv.x, acc[j]);
      acc[j] = fmaf(e1, wv.y, acc[j]);
      acc[j] = fmaf(e2, wv.z, acc[j]);
      acc[j] = fmaf(e3, wv.w, acc[j]);
    }
  }
  float* __restrict__ dst = (t ? Bb : A) + (size_t)b * Cn * PIX + (size_t)(og * 16) * PIX
                            + chunk * 256 + threadIdx.x;
#pragma unroll
  for (int j = 0; j < 16; ++j) dst[(size_t)j * PIX] = acc[j];
}

// ---------------------------------------------------------------------------
// K5: fused bilinear x4 upsample of A,B + residual combine:
//     out = F_dec + A_up * F_enc + B_up
// One thread per FOUR output pixels along W (one float4). For outputs
// 4k..4k+3: src x = k-0.375, k-0.125, k+0.125, k+0.375 -> needs only low-res
// columns {k-1, k, k+1} with compile-time x-weights {.625,.875,.125,.375}.
// Boundary clamps make both lerp endpoints equal, so fixed weights reproduce
// the reference (fx=0 cases) exactly.
__global__ __launch_bounds__(256) void k_final(
    const float* __restrict__ Fenc, const float* __restrict__ Fdec,
    const float* __restrict__ A, const float* __restrict__ Bb,
    float* __restrict__ out) {
  int idx = blockIdx.x * 256 + threadIdx.x;   // 16,777,216 float4 groups
  int k  = idx & 63;            // low-res x == output float4 index
  int h  = (idx >> 6) & 255;
  int bo = idx >> 14;           // b*C + o

  // vertical: PyTorch bilinear align_corners=False
  float sy = fmaxf((h + 0.5f) * 0.25f - 0.5f, 0.0f);
  int y0 = min((int)sy, 63);
  int y1 = min(y0 + 1, 63);
  float fy = sy - (float)y0;

  const float* __restrict__ Ap = A  + (size_t)bo * PIX;
  const float* __restrict__ Bp = Bb + (size_t)bo * PIX;
  int km1 = max(k - 1, 0), kp1 = min(k + 1, 63);
  int r0 = y0 << 6, r1 = y1 << 6;

  float aTL = Ap[r0 + km1], aTC = Ap[r0 + k], aTR = Ap[r0 + kp1];
  float aBL = Ap[r1 + km1], aBC = Ap[r1 + k], aBR = Ap[r1 + kp1];
  float bTL = Bp[r0 + km1], bTC = Bp[r0 + k], bTR = Bp[r0 + kp1];
  float bBL = Bp[r1 + km1], bBC = Bp[r1 + k], bBR = Bp[r1 + kp1];

  // y-interp the three needed columns
  float aL = aTL + (aBL - aTL) * fy;
  float aC = aTC + (aBC - aTC) * fy;
  float aR = aTR + (aBR - aTR) * fy;
  float bL = bTL + (bBL - bTL) * fy;
  float bC = bTC + (bBC - bTC) * fy;
  float bR = bTR + (bBR - bTR) * fy;

  // x-interp with fixed weights
  float4 av, bv;
  av.x = aL + (aC - aL) * 0.625f;
  av.y = aL + (aC - aL) * 0.875f;
  av.z = aC + (aR - aC) * 0.125f;
  av.w = aC + (aR - aC) * 0.375f;
  bv.x = bL + (bC - bL) * 0.625f;
  bv.y = bL + (bC - bL) * 0.875f;
  bv.z = bC + (bR - bC) * 0.125f;
  bv.w = bC + (bR - bC) * 0.375f;

  float4 e = ((const float4*)Fenc)[idx];
  float4 d = ((const float4*)Fdec)[idx];
  float4 o;
  o.x = fmaf(av.x, e.x, d.x + bv.x);
  o.y = fmaf(av.y, e.y, d.y + bv.y);
  o.z = fmaf(av.z, e.z, d.z + bv.z);
  o.w = fmaf(av.w, e.w, d.w + bv.w);
  ((float4*)out)[idx] = o;
}

// ---------------------------------------------------------------------------
extern "C" void kernel_launch(void* const* d_in, const int* in_sizes, int n_in,
                              void* d_out, int out_size, void* d_ws, size_t ws_size,
                              hipStream_t stream) {
  const float* F_enc = (const float*)d_in[0];
  const float* F_dec = (const float*)d_in[1];
  const float* w_rg  = (const float*)d_in[2];
  const float* w_rt  = (const float*)d_in[3];
  const float* w_ua  = (const float*)d_in[4];
  const float* w_ub  = (const float*)d_in[5];
  const float* eps   = (const float*)d_in[6];
  float* out = (float*)d_out;

  char* ws = (char*)d_ws;
  float* E_ds = (float*)(ws);                      // 16 MB; reused as A after K2
  float* D_ds = (float*)(ws + (16u << 20));        // 16 MB; reused as Bb after K2
  float* fg   = (float*)(ws + (32u << 20));        // 4 MB
  float* ft   = (float*)(ws + (36u << 20));        // 4 MB
  float* a_lr = (float*)(ws + (40u << 20));        // 4 MB
  float* b_lr = (float*)(ws + (44u << 20));        // 4 MB  (peak ws use: 48 MB)
  float* A  = E_ds;   // alias: E_ds dead after k_reduce_c
  float* Bb = D_ds;   // alias: D_ds dead after k_reduce_c

  // K1: downsample both feature maps: 1,048,576 float4 outputs each
  k_downsample<<<dim3(4096, 2), 256, 0, stream>>>(F_enc, F_dec, E_ds, D_ds);
  // K2: C->R reduce at low res (both tensors)
  k_reduce_c<<<dim3(16, 4, 8), 256, 0, stream>>>(E_ds, D_ds, w_rg, w_rt, fg, ft);
  // K3: box stats + a/b solve
  k_box_ab<<<4096, 256, 0, stream>>>(fg, ft, eps, a_lr, b_lr);
  // K4: R->C expand at low res
  k_expand_r<<<dim3(16, 16, 8), 256, 0, stream>>>(a_lr, b_lr, w_ua, w_ub, A, Bb);
  // K5: fused upsample + residual (float4 per thread)
  k_final<<<65536, 256, 0, stream>>>(F_enc, F_dec, A, Bb, out);
}